// Round 6
// baseline (198.396 us; speedup 1.0000x reference)
//
#include <hip/hip_runtime.h>
#include <hip/hip_bf16.h>

#define N_NODES 131072
#define BATCH 128
#define H 256
#define SPLIT 16   // chunks per GAP; grid = 128 gaps * SPLIT = 2048 blocks

typedef _Float16 half8 __attribute__((ext_vector_type(8)));
typedef float floatx4 __attribute__((ext_vector_type(4)));

// ---------------------------------------------------------------------------
// Pack W1 (f32 row-major KxN, K=H, N=H) into fragment-ordered f16 for
// mfma_f32_16x16x32_f16 B-operand.
// Chunk g = (ct*8 + ks)*64 + lane holds 8 f16:
//   W1[ks*32 + (lane>>4)*8 + j][ct*16 + (lane&15)], j=0..7
// ---------------------------------------------------------------------------
__global__ __launch_bounds__(256) void w1_pack_kernel(
    const float* __restrict__ W1, _Float16* __restrict__ W1p)
{
    const int g = blockIdx.x * 256 + threadIdx.x;   // [0, 8192)
    const int ct = g >> 9;
    const int ks = (g >> 6) & 7;
    const int l  = g & 63;
    const int k0 = ks * 32 + (l >> 4) * 8;
    const int col = ct * 16 + (l & 15);
    half8 h;
    #pragma unroll
    for (int j = 0; j < 8; ++j) h[j] = (_Float16)W1[(k0 + j) * H + col];
    reinterpret_cast<half8*>(W1p)[g] = h;
}

// ---------------------------------------------------------------------------
// FUSED stage 1+2a: per-(gap, chunk) block computes scores for its own rows
// via f16 MFMA, then online-softmax aggregates them. X crosses HBM once.
//
// Per 64-row tile:
//   1. stage X rows f32->f16 into XOR-swizzled LDS (pad rows zeroed)
//   2. 8x16 MFMA -> tanh -> W2 dot -> 64 scores in scLds (pad = -1e30)
//   3. online update: M = max(m, tile_max); rescale acc,z by exp(m-M);
//      accumulate p_i * x_i (f32 X re-read, L2-hot). m per-block uniform.
// Partial (m, z, acc) written per (gap, chunk) exactly as before.
// ---------------------------------------------------------------------------
__global__ __launch_bounds__(256) void fused_kernel(
    const float* __restrict__ X, const _Float16* __restrict__ W1p,
    const float* __restrict__ b1, const float* __restrict__ W2,
    const float* __restrict__ b2, const int* __restrict__ offsets,
    float* __restrict__ pm, float* __restrict__ pz, float* __restrict__ pacc)
{
    __shared__ __align__(16) _Float16 Xs[64 * H];   // 32 KB, swizzled
    __shared__ float sp[4][64];
    __shared__ float scLds[64];
    __shared__ float accLds[4][H];
    __shared__ float szw[4];

    const int gp = blockIdx.x >> 4;      // gap id, 0..127
    const int s = blockIdx.x & 15;       // chunk within gap
    const int tid = threadIdx.x;
    const int lane = tid & 63;
    const int wave = tid >> 6;

    const int gs = offsets[gp];
    const int ge = (gp == BATCH - 1) ? N_NODES : offsets[gp + 1];
    const int L = ge - gs;
    const int chunk = (L + SPLIT - 1) / SPLIT;
    const int cs = gs + s * chunk;
    const int ce = min(cs + chunk, ge);

    const float4* X4 = reinterpret_cast<const float4*>(X);
    const half8* Bv = reinterpret_cast<const half8*>(W1p);

    float w2v[4], b1v[4];
    #pragma unroll
    for (int ctl = 0; ctl < 4; ++ctl) {
        const int col = wave * 64 + ctl * 16 + (lane & 15);
        w2v[ctl] = W2[col];
        b1v[ctl] = b1[col];
    }
    const float bias2 = b2[0];

    float m = -1e30f;          // block-uniform running max
    float zw = 0.f;            // per-wave partial z (meaningful on lane 0)
    float4 accF = {0.f, 0.f, 0.f, 0.f};

    for (int t0 = cs; t0 < ce; t0 += 64) {
        const int valid = min(64, ce - t0);

        __syncthreads();   // prior tile fully consumed (Xs by MFMA, scLds by G)

        // ---- 1. stage tile ----
        #pragma unroll
        for (int i = 0; i < 8; ++i) {
            const int c = tid + i * 256;        // 2048 chunks of 8 f16
            const int row = c >> 5;
            const int col8 = c & 31;
            half8 h;
            if (row < valid) {
                float4 a  = X4[(long long)(t0 + row) * 64 + col8 * 2];
                float4 bq = X4[(long long)(t0 + row) * 64 + col8 * 2 + 1];
                h[0] = (_Float16)a.x;  h[1] = (_Float16)a.y;
                h[2] = (_Float16)a.z;  h[3] = (_Float16)a.w;
                h[4] = (_Float16)bq.x; h[5] = (_Float16)bq.y;
                h[6] = (_Float16)bq.z; h[7] = (_Float16)bq.w;
            } else {
                #pragma unroll
                for (int j = 0; j < 8; ++j) h[j] = (_Float16)0.f;
            }
            int byte = row * 512 + col8 * 16;
            byte ^= (row & 7) << 4;
            *reinterpret_cast<half8*>(reinterpret_cast<char*>(Xs) + byte) = h;
        }
        __syncthreads();

        // ---- 2. MFMA scores ----
        floatx4 acc[4][4];
        #pragma unroll
        for (int rt = 0; rt < 4; ++rt)
            #pragma unroll
            for (int ctl = 0; ctl < 4; ++ctl)
                acc[rt][ctl] = (floatx4){0.f, 0.f, 0.f, 0.f};

        #pragma unroll
        for (int ks = 0; ks < 8; ++ks) {
            half8 af[4];
            #pragma unroll
            for (int rt = 0; rt < 4; ++rt) {
                const int row = rt * 16 + (lane & 15);
                int byte = row * 512 + ks * 64 + (lane >> 4) * 16;
                byte ^= (row & 7) << 4;
                af[rt] = *reinterpret_cast<const half8*>(
                    reinterpret_cast<const char*>(Xs) + byte);
            }
            half8 bf[4];
            #pragma unroll
            for (int ctl = 0; ctl < 4; ++ctl) {
                const int ct = wave * 4 + ctl;
                bf[ctl] = Bv[(ct * 8 + ks) * 64 + lane];
            }
            #pragma unroll
            for (int rt = 0; rt < 4; ++rt)
                #pragma unroll
                for (int ctl = 0; ctl < 4; ++ctl)
                    acc[rt][ctl] = __builtin_amdgcn_mfma_f32_16x16x32_f16(
                        af[rt], bf[ctl], acc[rt][ctl], 0, 0, 0);
        }

        float sc[4][4];
        #pragma unroll
        for (int rt = 0; rt < 4; ++rt) {
            #pragma unroll
            for (int reg = 0; reg < 4; ++reg) {
                float sacc = 0.f;
                #pragma unroll
                for (int ctl = 0; ctl < 4; ++ctl) {
                    const float x = acc[rt][ctl][reg] + b1v[ctl];
                    const float t = 1.f - 2.f / (__expf(2.f * x) + 1.f);
                    sacc = fmaf(t, w2v[ctl], sacc);
                }
                sc[rt][reg] = sacc;
            }
        }
        #pragma unroll
        for (int off = 1; off < 16; off <<= 1)
            #pragma unroll
            for (int rt = 0; rt < 4; ++rt)
                #pragma unroll
                for (int reg = 0; reg < 4; ++reg)
                    sc[rt][reg] += __shfl_xor(sc[rt][reg], off);

        if ((lane & 15) == 0) {
            #pragma unroll
            for (int rt = 0; rt < 4; ++rt)
                #pragma unroll
                for (int reg = 0; reg < 4; ++reg)
                    sp[wave][rt * 16 + (lane >> 4) * 4 + reg] = sc[rt][reg];
        }
        __syncthreads();
        if (tid < 64)
            scLds[tid] = (tid < valid)
                ? sp[0][tid] + sp[1][tid] + sp[2][tid] + sp[3][tid] + bias2
                : -1e30f;
        __syncthreads();

        // ---- 3. online softmax aggregation ----
        float mt = -1e30f;
        #pragma unroll 8
        for (int j = 0; j < 64; ++j) mt = fmaxf(mt, scLds[j]);
        const float M = fmaxf(m, mt);
        const float r = __expf(m - M);
        accF.x *= r; accF.y *= r; accF.z *= r; accF.w *= r;
        zw *= r;
        for (int i = wave; i < valid; i += 4) {
            const float p = __expf(scLds[i] - M);
            float4 xv = X4[(long long)(t0 + i) * 64 + lane];
            accF.x = fmaf(p, xv.x, accF.x);
            accF.y = fmaf(p, xv.y, accF.y);
            accF.z = fmaf(p, xv.z, accF.z);
            accF.w = fmaf(p, xv.w, accF.w);
            if (lane == 0) zw += p;
        }
        m = M;
    }

    // ---- write per-(gap,chunk) partials ----
    __syncthreads();   // scLds/Xs no longer needed; reuse accLds region safely
    reinterpret_cast<float4*>(&accLds[wave][0])[lane] = accF;
    if (lane == 0) szw[wave] = zw;
    __syncthreads();
    const int pidx = blockIdx.x;
    pacc[(long long)pidx * H + tid] =
        accLds[0][tid] + accLds[1][tid] + accLds[2][tid] + accLds[3][tid];
    if (tid == 0) {
        pm[pidx] = m;
        pz[pidx] = szw[0] + szw[1] + szw[2] + szw[3];
    }
}

// ---------------------------------------------------------------------------
// Stage 2b: segment b = union of gaps [max(b-1,0), min(b+1,127)].
// Combine those gaps' chunk partials with max-rescaling.
// ---------------------------------------------------------------------------
__global__ __launch_bounds__(256) void reduce_kernel(
    const float* __restrict__ pm, const float* __restrict__ pz,
    const float* __restrict__ pacc, float* __restrict__ out)
{
    const int b = blockIdx.x;
    const int tid = threadIdx.x;
    const int g0 = (b == 0) ? 0 : b - 1;
    const int g1 = (b >= BATCH - 1) ? BATCH - 1 : b + 1;
    const int s0 = g0 * SPLIT;
    const int s1 = (g1 + 1) * SPLIT;   // exclusive

    float M = -1e30f;
    for (int s = s0; s < s1; ++s) M = fmaxf(M, pm[s]);

    float z = 0.f, r = 0.f;
    for (int s = s0; s < s1; ++s) {
        const float w = __expf(pm[s] - M);
        z = fmaf(pz[s], w, z);
        r = fmaf(pacc[(long long)s * H + tid], w, r);
    }
    out[b * H + tid] = r / z;
}

// ---------------------------------------------------------------------------
extern "C" void kernel_launch(void* const* d_in, const int* in_sizes, int n_in,
                              void* d_out, int out_size, void* d_ws, size_t ws_size,
                              hipStream_t stream)
{
    const float* X     = (const float*)d_in[0];
    const int* offs    = (const int*)d_in[1];   // int64 in ref -> int32 on device
    const float* W1    = (const float*)d_in[2];
    const float* b1    = (const float*)d_in[3];
    const float* W2    = (const float*)d_in[4];
    const float* b2    = (const float*)d_in[5];
    float* out         = (float*)d_out;

    // workspace layout (floats):
    //   [0, BS)              pm      (BS = 128 gaps * SPLIT = 2048)
    //   [BS, 2BS)            pz
    //   [2BS, 2BS+BS*H)      pacc
    //   [.., +32768)         W1p (65536 f16)
    float* pm     = (float*)d_ws;
    float* pz     = pm + BATCH * SPLIT;
    float* pacc   = pz + BATCH * SPLIT;
    _Float16* W1p = (_Float16*)(pacc + (size_t)BATCH * SPLIT * H);

    w1_pack_kernel<<<32, 256, 0, stream>>>(W1, W1p);
    fused_kernel<<<BATCH * SPLIT, 256, 0, stream>>>(X, W1p, b1, W2, b2, offs,
                                                    pm, pz, pacc);
    reduce_kernel<<<BATCH, 256, 0, stream>>>(pm, pz, pacc, out);
}

// Round 7
// 89.743 us; speedup vs baseline: 2.2107x; 2.2107x over previous
//
#include <hip/hip_runtime.h>
#include <hip/hip_bf16.h>

#define N_NODES 131072
#define BATCH 128
#define H 256
#define SPLIT 16   // chunks per GAP; grid = 128 gaps * SPLIT = 2048 blocks

typedef _Float16 half8 __attribute__((ext_vector_type(8)));
typedef float floatx4 __attribute__((ext_vector_type(4)));

// ---------------------------------------------------------------------------
// Pack W1 (f32 row-major KxN, K=H, N=H) into fragment-ordered f16 for
// mfma_f32_16x16x32_f16 B-operand.
// Chunk g = (ct*8 + ks)*64 + lane holds 8 f16:
//   W1[ks*32 + (lane>>4)*8 + j][ct*16 + (lane&15)], j=0..7
// ---------------------------------------------------------------------------
__global__ __launch_bounds__(256) void w1_pack_kernel(
    const float* __restrict__ W1, _Float16* __restrict__ W1p)
{
    const int g = blockIdx.x * 256 + threadIdx.x;   // [0, 8192)
    const int ct = g >> 9;
    const int ks = (g >> 6) & 7;
    const int l  = g & 63;
    const int k0 = ks * 32 + (l >> 4) * 8;
    const int col = ct * 16 + (l & 15);
    half8 h;
    #pragma unroll
    for (int j = 0; j < 8; ++j) h[j] = (_Float16)W1[(k0 + j) * H + col];
    reinterpret_cast<half8*>(W1p)[g] = h;
}

// ---------------------------------------------------------------------------
// Stage 1: escore[n] = exp(tanh(X[n,:] @ W1 + b1) @ W2 + b2) via f16 MFMA.
// Staging restructured: ALL 16 global dwordx4 loads issued per thread before
// any convert/ds_write, so the full 64KB tile is in flight (HBM latency
// hiding at 8 waves/CU). Exp folded into the epilogue (max-free softmax:
// |score| <= ||W2||_1 + |b2| ~ 13 -> exp in [2e-6, 4e5], f32-safe).
// ---------------------------------------------------------------------------
__global__ __launch_bounds__(256) void scores_mfma_kernel(
    const float* __restrict__ X, const _Float16* __restrict__ W1p,
    const float* __restrict__ b1, const float* __restrict__ W2,
    const float* __restrict__ b2, float* __restrict__ escore)
{
    __shared__ __align__(16) _Float16 Xs[64 * H];   // 32 KB, swizzled
    __shared__ float sp[4][64];

    const int tid = threadIdx.x;
    const int wave = tid >> 6;
    const int lane = tid & 63;
    const long long base = (long long)blockIdx.x * 64;

    // ---- stage X tile: issue all loads, then convert+write ----
    {
        const float4* Xv = reinterpret_cast<const float4*>(X + base * H);
        float4 va[8], vb[8];
        #pragma unroll
        for (int i = 0; i < 8; ++i) {
            const int c = tid + i * 256;
            const int row = c >> 5;
            const int col8 = c & 31;
            va[i] = Xv[row * 64 + col8 * 2];
            vb[i] = Xv[row * 64 + col8 * 2 + 1];
        }
        #pragma unroll
        for (int i = 0; i < 8; ++i) {
            const int c = tid + i * 256;
            const int row = c >> 5;
            const int col8 = c & 31;
            half8 h;
            h[0] = (_Float16)va[i].x; h[1] = (_Float16)va[i].y;
            h[2] = (_Float16)va[i].z; h[3] = (_Float16)va[i].w;
            h[4] = (_Float16)vb[i].x; h[5] = (_Float16)vb[i].y;
            h[6] = (_Float16)vb[i].z; h[7] = (_Float16)vb[i].w;
            int byte = row * 512 + col8 * 16;
            byte ^= (row & 7) << 4;
            *reinterpret_cast<half8*>(reinterpret_cast<char*>(Xs) + byte) = h;
        }
    }
    __syncthreads();

    floatx4 acc[4][4];
    #pragma unroll
    for (int rt = 0; rt < 4; ++rt)
        #pragma unroll
        for (int ctl = 0; ctl < 4; ++ctl)
            acc[rt][ctl] = (floatx4){0.f, 0.f, 0.f, 0.f};

    const half8* Bv = reinterpret_cast<const half8*>(W1p);

    #pragma unroll
    for (int ks = 0; ks < 8; ++ks) {
        half8 af[4];
        #pragma unroll
        for (int rt = 0; rt < 4; ++rt) {
            const int row = rt * 16 + (lane & 15);
            int byte = row * 512 + ks * 64 + (lane >> 4) * 16;
            byte ^= (row & 7) << 4;
            af[rt] = *reinterpret_cast<const half8*>(
                reinterpret_cast<const char*>(Xs) + byte);
        }
        half8 bf[4];
        #pragma unroll
        for (int ctl = 0; ctl < 4; ++ctl) {
            const int ct = wave * 4 + ctl;
            bf[ctl] = Bv[(ct * 8 + ks) * 64 + lane];
        }
        #pragma unroll
        for (int rt = 0; rt < 4; ++rt)
            #pragma unroll
            for (int ctl = 0; ctl < 4; ++ctl)
                acc[rt][ctl] = __builtin_amdgcn_mfma_f32_16x16x32_f16(
                    af[rt], bf[ctl], acc[rt][ctl], 0, 0, 0);
    }

    // ---- epilogue: tanh + W2 dot + exp ----
    float w2v[4], b1v[4];
    #pragma unroll
    for (int ctl = 0; ctl < 4; ++ctl) {
        const int col = wave * 64 + ctl * 16 + (lane & 15);
        w2v[ctl] = W2[col];
        b1v[ctl] = b1[col];
    }

    float sc[4][4];
    #pragma unroll
    for (int rt = 0; rt < 4; ++rt) {
        #pragma unroll
        for (int reg = 0; reg < 4; ++reg) {
            float s = 0.f;
            #pragma unroll
            for (int ctl = 0; ctl < 4; ++ctl) {
                const float x = acc[rt][ctl][reg] + b1v[ctl];
                const float t = 1.f - 2.f / (__expf(2.f * x) + 1.f);
                s = fmaf(t, w2v[ctl], s);
            }
            sc[rt][reg] = s;
        }
    }
    #pragma unroll
    for (int off = 1; off < 16; off <<= 1)
        #pragma unroll
        for (int rt = 0; rt < 4; ++rt)
            #pragma unroll
            for (int reg = 0; reg < 4; ++reg)
                sc[rt][reg] += __shfl_xor(sc[rt][reg], off);

    if ((lane & 15) == 0) {
        #pragma unroll
        for (int rt = 0; rt < 4; ++rt)
            #pragma unroll
            for (int reg = 0; reg < 4; ++reg)
                sp[wave][rt * 16 + (lane >> 4) * 4 + reg] = sc[rt][reg];
    }
    __syncthreads();
    if (tid < 64)
        escore[base + tid] =
            __expf(sp[0][tid] + sp[1][tid] + sp[2][tid] + sp[3][tid] + b2[0]);
}

// ---------------------------------------------------------------------------
// Stage 2a: per-(gap, chunk) single-pass aggregation (max-free).
// gap g = [offsets[g], offsets[g+1]) (g=127 -> N). Wave w handles rows
// i == w (mod 4); p = escore[i] is a wave-uniform load; acc += p*x;
// z += p (identical across lanes). No LDS broadcast, no in-loop syncs.
// ---------------------------------------------------------------------------
__global__ __launch_bounds__(256) void partial_kernel(
    const float* __restrict__ X, const float* __restrict__ escore,
    const int* __restrict__ offsets,
    float* __restrict__ pz, float* __restrict__ pacc)
{
    const int gp = blockIdx.x >> 4;      // gap id, 0..127
    const int s = blockIdx.x & 15;       // chunk within gap
    const int tid = threadIdx.x;
    const int lane = tid & 63;
    const int wave = tid >> 6;

    const int gs = offsets[gp];
    const int ge = (gp == BATCH - 1) ? N_NODES : offsets[gp + 1];
    const int L = ge - gs;
    const int chunk = (L + SPLIT - 1) / SPLIT;
    const int cs = gs + s * chunk;
    const int ce = min(cs + chunk, ge);

    const float4* X4 = reinterpret_cast<const float4*>(X);

    float4 acc = {0.f, 0.f, 0.f, 0.f};
    float z = 0.f;
    for (int i = cs + wave; i < ce; i += 4) {
        const float p = escore[i];
        float4 xv = X4[(long long)i * 64 + lane];
        acc.x = fmaf(p, xv.x, acc.x);
        acc.y = fmaf(p, xv.y, acc.y);
        acc.z = fmaf(p, xv.z, acc.z);
        acc.w = fmaf(p, xv.w, acc.w);
        z += p;
    }

    __shared__ float accL[4][H];
    __shared__ float zL[4];
    reinterpret_cast<float4*>(&accL[wave][0])[lane] = acc;
    if (lane == 0) zL[wave] = z;
    __syncthreads();
    pacc[(long long)blockIdx.x * H + tid] =
        accL[0][tid] + accL[1][tid] + accL[2][tid] + accL[3][tid];
    if (tid == 0) pz[blockIdx.x] = zL[0] + zL[1] + zL[2] + zL[3];
}

// ---------------------------------------------------------------------------
// Stage 2b: segment b = union of gaps [max(b-1,0), min(b+1,127)].
// Plain sums (max-free), out = r / z.
// ---------------------------------------------------------------------------
__global__ __launch_bounds__(256) void reduce_kernel(
    const float* __restrict__ pz, const float* __restrict__ pacc,
    float* __restrict__ out)
{
    const int b = blockIdx.x;
    const int tid = threadIdx.x;
    const int g0 = (b == 0) ? 0 : b - 1;
    const int g1 = (b >= BATCH - 1) ? BATCH - 1 : b + 1;
    const int s0 = g0 * SPLIT;
    const int s1 = (g1 + 1) * SPLIT;   // exclusive

    float z = 0.f, r = 0.f;
    for (int s = s0; s < s1; ++s) {
        z += pz[s];
        r += pacc[(long long)s * H + tid];
    }
    out[b * H + tid] = r / z;
}

// ---------------------------------------------------------------------------
extern "C" void kernel_launch(void* const* d_in, const int* in_sizes, int n_in,
                              void* d_out, int out_size, void* d_ws, size_t ws_size,
                              hipStream_t stream)
{
    const float* X     = (const float*)d_in[0];
    const int* offs    = (const int*)d_in[1];   // int64 in ref -> int32 on device
    const float* W1    = (const float*)d_in[2];
    const float* b1    = (const float*)d_in[3];
    const float* W2    = (const float*)d_in[4];
    const float* b2    = (const float*)d_in[5];
    float* out         = (float*)d_out;

    // workspace layout (floats):
    //   [0, N)               escore
    //   [N, N+BS)            pz      (BS = 2048)
    //   [N+BS, N+BS+BS*H)    pacc
    //   [.., +32768)         W1p (65536 f16)
    float* escore = (float*)d_ws;
    float* pz     = escore + N_NODES;
    float* pacc   = pz + BATCH * SPLIT;
    _Float16* W1p = (_Float16*)(pacc + (size_t)BATCH * SPLIT * H);

    w1_pack_kernel<<<32, 256, 0, stream>>>(W1, W1p);
    scores_mfma_kernel<<<N_NODES / 64, 256, 0, stream>>>(X, W1p, b1, W2, b2, escore);
    partial_kernel<<<BATCH * SPLIT, 256, 0, stream>>>(X, escore, offs, pz, pacc);
    reduce_kernel<<<BATCH, 256, 0, stream>>>(pz, pacc, out);
}